// Round 3
// baseline (780.102 us; speedup 1.0000x reference)
//
#include <hip/hip_runtime.h>
#include <hip/hip_bf16.h>

typedef __attribute__((ext_vector_type(8))) __bf16 bf16x8;
typedef __attribute__((ext_vector_type(4))) float f32x4;

// ---------------------------------------------------------------------------
// FP4 E2M1 fake-quant helpers (bit-exact vs reference):
//   scale = max(absmax/6, 1e-12)   [fp32 div]
//   mag   = |x| / scale            [fp32 div]
//   idx   = #{mids < mag}  (strict >, ties round DOWN = searchsorted left)
// Returns bf16 bits of grid[idx] * sign(x). Grid values are exact in bf16.
// ---------------------------------------------------------------------------
__device__ __forceinline__ unsigned short fp4_q_bf16(float x, float scale) {
    float mag = fabsf(x) / scale;
    float g = mag > 2.5f ? (mag > 5.0f ? 6.0f : (mag > 3.5f ? 4.0f : 3.0f))
                         : (mag > 1.25f ? (mag > 1.75f ? 2.0f : 1.5f)
                                        : (mag > 0.75f ? 1.0f
                                                       : (mag > 0.25f ? 0.5f : 0.0f)));
    unsigned gb = __float_as_uint(g) >> 16;                 // exact truncation
    unsigned sb = (__float_as_uint(x) >> 16) & 0x8000u;     // sign bit
    return (unsigned short)(gb | sb);
}

__device__ __forceinline__ float load_scale(const unsigned* amax_bits) {
    float am = __uint_as_float(*amax_bits);
    return fmaxf(am / 6.0f, 1e-12f);
}

// ---------------------------------------------------------------------------
// 1) absmax reduction: float4 grid-stride, wave reduce, atomicMax on uint bits
// ---------------------------------------------------------------------------
__global__ void absmax_kernel(const float4* __restrict__ in, long long n4,
                              unsigned* __restrict__ out) {
    float m = 0.0f;
    long long stride = (long long)gridDim.x * blockDim.x;
    for (long long i = (long long)blockIdx.x * blockDim.x + threadIdx.x; i < n4; i += stride) {
        float4 v = in[i];
        m = fmaxf(m, fmaxf(fmaxf(fabsf(v.x), fabsf(v.y)), fmaxf(fabsf(v.z), fabsf(v.w))));
    }
    #pragma unroll
    for (int off = 32; off > 0; off >>= 1)
        m = fmaxf(m, __shfl_xor(m, off));
    if ((threadIdx.x & 63) == 0)
        atomicMax(out, __float_as_uint(m));   // valid: all values non-negative
}

// ---------------------------------------------------------------------------
// 2) quantize x -> bf16 (row-major [M][K] unchanged)
// ---------------------------------------------------------------------------
__global__ void quant_kernel(const float4* __restrict__ in,
                             const unsigned* __restrict__ amax_bits,
                             ushort4* __restrict__ out, long long n4) {
    float scale = load_scale(amax_bits);
    long long stride = (long long)gridDim.x * blockDim.x;
    for (long long i = (long long)blockIdx.x * blockDim.x + threadIdx.x; i < n4; i += stride) {
        float4 v = in[i];
        ushort4 o;
        o.x = fp4_q_bf16(v.x, scale);
        o.y = fp4_q_bf16(v.y, scale);
        o.z = fp4_q_bf16(v.z, scale);
        o.w = fp4_q_bf16(v.w, scale);
        out[i] = o;
    }
}

// ---------------------------------------------------------------------------
// 3) quantize + transpose w [K][N] fp32 -> wqT [N][K] bf16 (64x64 LDS tile)
// ---------------------------------------------------------------------------
__global__ __launch_bounds__(256)
void quant_w_t_kernel(const float* __restrict__ w,
                      const unsigned* __restrict__ amax_bits,
                      unsigned short* __restrict__ wqT, int N, int K) {
    __shared__ unsigned short tile[64][65];   // +1 pad breaks bank conflicts
    float scale = load_scale(amax_bits);
    int t = threadIdx.x;
    int bk = blockIdx.x;   // K-tile
    int bn = blockIdx.y;   // N-tile
    int r0 = t >> 4;        // 0..15
    int c4 = (t & 15) * 4;  // 0..60
    #pragma unroll
    for (int i = 0; i < 4; ++i) {
        int r = r0 + i * 16;
        float4 v = *(const float4*)&w[(size_t)(bk * 64 + r) * N + bn * 64 + c4];
        tile[r][c4 + 0] = fp4_q_bf16(v.x, scale);
        tile[r][c4 + 1] = fp4_q_bf16(v.y, scale);
        tile[r][c4 + 2] = fp4_q_bf16(v.z, scale);
        tile[r][c4 + 3] = fp4_q_bf16(v.w, scale);
    }
    __syncthreads();
    #pragma unroll
    for (int i = 0; i < 4; ++i) {
        int rr = r0 + i * 16;   // output row (n offset)
        ushort4 o;
        o.x = tile[c4 + 0][rr];
        o.y = tile[c4 + 1][rr];
        o.z = tile[c4 + 2][rr];
        o.w = tile[c4 + 3][rr];
        *(ushort4*)&wqT[(size_t)(bn * 64 + rr) * K + bk * 64 + c4] = o;
    }
}

// ---------------------------------------------------------------------------
// 4) bf16 GEMM: A=[M][K] row-major, B=wqT [N][K] row-major, C=[M][N] fp32
//    128x128 tile, BK=64, 4 waves (2x2), 16x16x32 MFMA
//    global_load_lds width=16, both-sides XOR swizzle (slot ^= row&7)
// ---------------------------------------------------------------------------
__device__ __forceinline__ void gload_lds16(const unsigned short* g, unsigned short* l) {
    __builtin_amdgcn_global_load_lds(
        (const __attribute__((address_space(1))) unsigned int*)g,
        (__attribute__((address_space(3))) unsigned int*)l, 16, 0, 0);
}

__global__ __launch_bounds__(256)
void gemm_kernel(const unsigned short* __restrict__ A,   // xq  [M][K]
                 const unsigned short* __restrict__ B,   // wqT [N][K]
                 const unsigned* __restrict__ amax_bits, // [0]=x [1]=w
                 const float* __restrict__ bias,
                 float* __restrict__ C, int M, int N, int K) {
    __shared__ unsigned short As[128 * 64];  // 16 KB, rows of 64 bf16 (8 slots x 16B)
    __shared__ unsigned short Bs[128 * 64];  // 16 KB

    int tid  = threadIdx.x;
    int wave = tid >> 6;
    int lane = tid & 63;

    // XCD-aware bijective swizzle (grid % 8 == 0 here: 2048 blocks)
    int nbn = N >> 7;
    int bx  = blockIdx.x;
    int cpx = gridDim.x >> 3;
    int swz = (bx & 7) * cpx + (bx >> 3);
    int bm  = swz / nbn;
    int bn  = swz % nbn;

    float sx  = load_scale(amax_bits + 0);
    float sw  = load_scale(amax_bits + 1);
    float sxw = sx * sw;

    int wrow = wave >> 1;           // 0..1
    int wcol = wave & 1;            // 0..1
    int lrow = lane >> 3;           // 0..7 (staging row within 8-row chunk)
    int slot = lane & 7;            // 0..7 (staging 16B slot)
    int sswz = slot ^ lrow;         // pre-swizzled global slot (row&7 == lrow)

    size_t a_base = (size_t)(bm * 128) * K;
    size_t b_base = (size_t)(bn * 128) * K;

    int l15 = lane & 15;
    int l4  = lane >> 4;            // k-group 0..3
    int r7  = lane & 7;             // row&7 for fragment reads

    f32x4 acc[4][4] = {};

    for (int kt = 0; kt < K; kt += 64) {
        // ---- stage A,B tiles (16B global_load_lds, linear LDS dest) ----
        #pragma unroll
        for (int i = 0; i < 4; ++i) {
            int chunk = wave * 4 + i;            // 0..15, 8 rows each
            int row   = chunk * 8 + lrow;
            size_t go = (size_t)row * K + kt + sswz * 8;
            gload_lds16(A + a_base + go, &As[chunk * 512]);
            gload_lds16(B + b_base + go, &Bs[chunk * 512]);
        }
        __syncthreads();   // compiler drains vmcnt before barrier

        // ---- compute: 2 K-steps of 32, 16 MFMA each ----
        #pragma unroll
        for (int kk = 0; kk < 2; ++kk) {
            bf16x8 af[4], bfr[4];
            #pragma unroll
            for (int mi = 0; mi < 4; ++mi) {
                int row = wrow * 64 + mi * 16 + l15;
                int sl  = (kk * 4 + l4) ^ r7;    // swizzled read slot
                af[mi] = *(const bf16x8*)&As[row * 64 + sl * 8];
            }
            #pragma unroll
            for (int ni = 0; ni < 4; ++ni) {
                int row = wcol * 64 + ni * 16 + l15;
                int sl  = (kk * 4 + l4) ^ r7;
                bfr[ni] = *(const bf16x8*)&Bs[row * 64 + sl * 8];
            }
            #pragma unroll
            for (int mi = 0; mi < 4; ++mi)
                #pragma unroll
                for (int ni = 0; ni < 4; ++ni)
                    acc[mi][ni] = __builtin_amdgcn_mfma_f32_16x16x32_bf16(
                        af[mi], bfr[ni], acc[mi][ni], 0, 0, 0);
        }
        __syncthreads();
    }

    // ---- epilogue: C = acc * (sx*sw) + bias ----
    int r0 = bm * 128 + wrow * 64;
    int c0 = bn * 128 + wcol * 64;
    #pragma unroll
    for (int ni = 0; ni < 4; ++ni) {
        int col = c0 + ni * 16 + l15;
        float bv = bias[col];
        #pragma unroll
        for (int mi = 0; mi < 4; ++mi) {
            int rbase = r0 + mi * 16 + l4 * 4;
            #pragma unroll
            for (int j = 0; j < 4; ++j)
                C[(size_t)(rbase + j) * N + col] = acc[mi][ni][j] * sxw + bv;
        }
    }
}

// ---------------------------------------------------------------------------
extern "C" void kernel_launch(void* const* d_in, const int* in_sizes, int n_in,
                              void* d_out, int out_size, void* d_ws, size_t ws_size,
                              hipStream_t stream) {
    const float* x    = (const float*)d_in[0];
    const float* w    = (const float*)d_in[1];
    const float* bias = (const float*)d_in[2];
    float* out        = (float*)d_out;

    int N = in_sizes[2];            // 4096
    int K = in_sizes[1] / N;        // 4096
    int M = in_sizes[0] / K;        // 8192

    unsigned* amax        = (unsigned*)d_ws;                       // [0]=x [1]=w
    unsigned short* xq    = (unsigned short*)((char*)d_ws + 256);  // [M][K] bf16
    unsigned short* wqT   = (unsigned short*)((char*)xq + (size_t)M * K * 2); // [N][K]

    hipMemsetAsync(d_ws, 0, 256, stream);   // zero absmax accumulators

    long long nx4 = (long long)M * K / 4;
    long long nw4 = (long long)K * N / 4;

    absmax_kernel<<<1024, 256, 0, stream>>>((const float4*)x, nx4, amax + 0);
    absmax_kernel<<<1024, 256, 0, stream>>>((const float4*)w, nw4, amax + 1);

    quant_kernel<<<2048, 256, 0, stream>>>((const float4*)x, amax + 0, (ushort4*)xq, nx4);
    quant_w_t_kernel<<<dim3(K / 64, N / 64), 256, 0, stream>>>(w, amax + 1, wqT, N, K);

    dim3 grid((M / 128) * (N / 128));
    gemm_kernel<<<grid, 256, 0, stream>>>(xq, wqT, amax, bias, out, M, N, K);
}

// Round 4
// 631.464 us; speedup vs baseline: 1.2354x; 1.2354x over previous
//
#include <hip/hip_runtime.h>
#include <hip/hip_bf16.h>

typedef __attribute__((ext_vector_type(8))) __bf16 bf16x8;
typedef __attribute__((ext_vector_type(4))) float f32x4;

// ---------------------------------------------------------------------------
// FP4 E2M1 fake-quant helpers (bit-exact vs reference):
//   scale = max(absmax/6, 1e-12); mag = |x|/scale (IEEE div);
//   idx = #{mids < mag} (strict >, ties down = searchsorted left)
// Grid values exact in bf16.
// ---------------------------------------------------------------------------
__device__ __forceinline__ unsigned short fp4_q_bf16(float x, float scale) {
    float mag = fabsf(x) / scale;
    float g = mag > 2.5f ? (mag > 5.0f ? 6.0f : (mag > 3.5f ? 4.0f : 3.0f))
                         : (mag > 1.25f ? (mag > 1.75f ? 2.0f : 1.5f)
                                        : (mag > 0.75f ? 1.0f
                                                       : (mag > 0.25f ? 0.5f : 0.0f)));
    unsigned gb = __float_as_uint(g) >> 16;
    unsigned sb = (__float_as_uint(x) >> 16) & 0x8000u;
    return (unsigned short)(gb | sb);
}

__device__ __forceinline__ float load_scale(const unsigned* amax_bits) {
    float am = __uint_as_float(*amax_bits);
    return fmaxf(am / 6.0f, 1e-12f);
}

// ---------------------------------------------------------------------------
// 1) absmax reduction
// ---------------------------------------------------------------------------
__global__ void absmax_kernel(const float4* __restrict__ in, long long n4,
                              unsigned* __restrict__ out) {
    float m = 0.0f;
    long long stride = (long long)gridDim.x * blockDim.x;
    for (long long i = (long long)blockIdx.x * blockDim.x + threadIdx.x; i < n4; i += stride) {
        float4 v = in[i];
        m = fmaxf(m, fmaxf(fmaxf(fabsf(v.x), fabsf(v.y)), fmaxf(fabsf(v.z), fabsf(v.w))));
    }
    #pragma unroll
    for (int off = 32; off > 0; off >>= 1)
        m = fmaxf(m, __shfl_xor(m, off));
    if ((threadIdx.x & 63) == 0)
        atomicMax(out, __float_as_uint(m));
}

// ---------------------------------------------------------------------------
// 2) quantize x -> bf16 [M][K]
// ---------------------------------------------------------------------------
__global__ void quant_kernel(const float4* __restrict__ in,
                             const unsigned* __restrict__ amax_bits,
                             ushort4* __restrict__ out, long long n4) {
    float scale = load_scale(amax_bits);
    long long stride = (long long)gridDim.x * blockDim.x;
    for (long long i = (long long)blockIdx.x * blockDim.x + threadIdx.x; i < n4; i += stride) {
        float4 v = in[i];
        ushort4 o;
        o.x = fp4_q_bf16(v.x, scale);
        o.y = fp4_q_bf16(v.y, scale);
        o.z = fp4_q_bf16(v.z, scale);
        o.w = fp4_q_bf16(v.w, scale);
        out[i] = o;
    }
}

// ---------------------------------------------------------------------------
// 3) quantize + transpose w [K][N] fp32 -> wqT [N][K] bf16
// ---------------------------------------------------------------------------
__global__ __launch_bounds__(256)
void quant_w_t_kernel(const float* __restrict__ w,
                      const unsigned* __restrict__ amax_bits,
                      unsigned short* __restrict__ wqT, int N, int K) {
    __shared__ unsigned short tile[64][65];
    float scale = load_scale(amax_bits);
    int t = threadIdx.x;
    int bk = blockIdx.x, bn = blockIdx.y;
    int r0 = t >> 4;
    int c4 = (t & 15) * 4;
    #pragma unroll
    for (int i = 0; i < 4; ++i) {
        int r = r0 + i * 16;
        float4 v = *(const float4*)&w[(size_t)(bk * 64 + r) * N + bn * 64 + c4];
        tile[r][c4 + 0] = fp4_q_bf16(v.x, scale);
        tile[r][c4 + 1] = fp4_q_bf16(v.y, scale);
        tile[r][c4 + 2] = fp4_q_bf16(v.z, scale);
        tile[r][c4 + 3] = fp4_q_bf16(v.w, scale);
    }
    __syncthreads();
    #pragma unroll
    for (int i = 0; i < 4; ++i) {
        int rr = r0 + i * 16;
        ushort4 o;
        o.x = tile[c4 + 0][rr];
        o.y = tile[c4 + 1][rr];
        o.z = tile[c4 + 2][rr];
        o.w = tile[c4 + 3][rr];
        *(ushort4*)&wqT[(size_t)(bn * 64 + rr) * K + bk * 64 + c4] = o;
    }
}

// ---------------------------------------------------------------------------
// 4) 256x256 8-phase bf16 GEMM (T2+T3+T4+T5), A=[M][K], B=wqT[N][K], C fp32
//    8 waves (2M x 4N), per-wave 128x64, BK=64, LDS 128KB double-buffer.
//    Swizzle: LDS[row][slot] = global[row][slot ^ (row&7)] (16B slots).
// ---------------------------------------------------------------------------
__device__ __forceinline__ void gload_lds16(const unsigned short* g, unsigned short* l) {
    __builtin_amdgcn_global_load_lds(
        (const __attribute__((address_space(1))) unsigned int*)g,
        (__attribute__((address_space(3))) unsigned int*)l, 16, 0, 0);
}

// stage 64 rows (j4-th quarter) of one 256x64 operand tile; dest linear,
// source pre-swizzled. lbase wave-uniform; HW adds lane*16.
__device__ __forceinline__ void stage_op(const unsigned short* __restrict__ G,
                                         unsigned short* lbase, int K,
                                         int kt, int j4, int wave, int lane) {
    int rloc = j4 * 64 + wave * 8;              // wave-uniform row base
    int row  = rloc + (lane >> 3);              // row&7 == lane>>3
    int slot = (lane & 7) ^ (lane >> 3);        // pre-swizzled source slot
    size_t go = (size_t)row * K + kt + slot * 8;
    gload_lds16(G + go, lbase + (size_t)rloc * 64);
}

__global__ __launch_bounds__(512, 2)
void gemm256_kernel(const unsigned short* __restrict__ A,   // xq  [M][K]
                    const unsigned short* __restrict__ B,   // wqT [N][K]
                    const unsigned* __restrict__ amax_bits,
                    const float* __restrict__ bias,
                    float* __restrict__ C, int M, int N, int K) {
    // 2 bufs x (A 256x64 + B 256x64) bf16 = 128 KiB
    __shared__ unsigned short smem[65536];

    int tid = threadIdx.x;
    int wave = tid >> 6, lane = tid & 63;
    int wr = wave >> 2, wc = wave & 3;          // 2M x 4N wave grid
    int l15 = lane & 15, l4 = lane >> 4, l7 = lane & 7;

    // XCD-aware bijective swizzle (512 blocks % 8 == 0)
    int nbn = N >> 8;                            // 16
    int cpx = gridDim.x >> 3;
    int swz = ((int)blockIdx.x & 7) * cpx + ((int)blockIdx.x >> 3);
    int bm = swz / nbn, bn = swz % nbn;

    float sxw = load_scale(amax_bits + 0) * load_scale(amax_bits + 1);

    const unsigned short* Ag = A + (size_t)(bm * 256) * K;
    const unsigned short* Bg = B + (size_t)(bn * 256) * K;

    // ---- prologue: stage tile 0 into buf0 ----
    #pragma unroll
    for (int j4 = 0; j4 < 4; ++j4) stage_op(Ag, smem,         K, 0, j4, wave, lane);
    #pragma unroll
    for (int j4 = 0; j4 < 4; ++j4) stage_op(Bg, smem + 16384, K, 0, j4, wave, lane);
    asm volatile("s_waitcnt vmcnt(0)" ::: "memory");
    __builtin_amdgcn_s_barrier();

    f32x4 acc[8][4] = {};
    int NT = K >> 6;
    int cur = 0;

    for (int t = 0; t < NT; ++t) {
        unsigned short* As_ = smem + cur * 32768;
        unsigned short* Bs_ = As_ + 16384;
        unsigned short* An_ = smem + (cur ^ 1) * 32768;
        unsigned short* Bn_ = An_ + 16384;
        int ktn = (t + 1) << 6;
        bool pf = (t + 1 < NT);

        bf16x8 bfrag[2][4];   // B resident across the 4 phases

        #pragma unroll
        for (int q = 0; q < 4; ++q) {
            bf16x8 afrag[2][2];
            // ds-load A subtile for this phase (M-frags 2q, 2q+1)
            #pragma unroll
            for (int s = 0; s < 2; ++s) {
                int row = wr * 128 + (2 * q + s) * 16 + l15;   // row&7 == l7
                #pragma unroll
                for (int kk = 0; kk < 2; ++kk) {
                    int slot = (kk * 4 + l4) ^ l7;
                    afrag[kk][s] = *(const bf16x8*)&As_[row * 64 + slot * 8];
                }
            }
            if (q == 0) {
                // B full read (8 x b128) + prefetch A of next tile
                #pragma unroll
                for (int ni = 0; ni < 4; ++ni) {
                    int row = wc * 64 + ni * 16 + l15;
                    #pragma unroll
                    for (int kk = 0; kk < 2; ++kk) {
                        int slot = (kk * 4 + l4) ^ l7;
                        bfrag[kk][ni] = *(const bf16x8*)&Bs_[row * 64 + slot * 8];
                    }
                }
                if (pf) {
                    #pragma unroll
                    for (int j4 = 0; j4 < 4; ++j4)
                        stage_op(Ag, An_, K, ktn, j4, wave, lane);
                }
            }
            if (q == 1 && pf) {
                #pragma unroll
                for (int j4 = 0; j4 < 4; ++j4)
                    stage_op(Bg, Bn_, K, ktn, j4, wave, lane);
            }

            __builtin_amdgcn_s_barrier();
            asm volatile("s_waitcnt lgkmcnt(0)" ::: "memory");
            __builtin_amdgcn_sched_barrier(0);
            __builtin_amdgcn_s_setprio(1);
            #pragma unroll
            for (int kk = 0; kk < 2; ++kk)
                #pragma unroll
                for (int s = 0; s < 2; ++s)
                    #pragma unroll
                    for (int ni = 0; ni < 4; ++ni)
                        acc[2 * q + s][ni] = __builtin_amdgcn_mfma_f32_16x16x32_bf16(
                            afrag[kk][s], bfrag[kk][ni], acc[2 * q + s][ni], 0, 0, 0);
            __builtin_amdgcn_s_setprio(0);
            if (q == 3) {
                // counted wait: only next-tile prefetch loads are outstanding
                asm volatile("s_waitcnt vmcnt(0)" ::: "memory");
            }
            __builtin_amdgcn_s_barrier();
        }
        cur ^= 1;
    }

    // ---- epilogue: C = acc * sxw + bias ----
    int r0 = bm * 256 + wr * 128;
    int c0 = bn * 256 + wc * 64;
    #pragma unroll
    for (int ni = 0; ni < 4; ++ni) {
        int col = c0 + ni * 16 + l15;
        float bv = bias[col];
        #pragma unroll
        for (int mi = 0; mi < 8; ++mi) {
            int rbase = r0 + mi * 16 + l4 * 4;
            #pragma unroll
            for (int j = 0; j < 4; ++j)
                C[(size_t)(rbase + j) * N + col] = acc[mi][ni][j] * sxw + bv;
        }
    }
}

// ---------------------------------------------------------------------------
extern "C" void kernel_launch(void* const* d_in, const int* in_sizes, int n_in,
                              void* d_out, int out_size, void* d_ws, size_t ws_size,
                              hipStream_t stream) {
    const float* x    = (const float*)d_in[0];
    const float* w    = (const float*)d_in[1];
    const float* bias = (const float*)d_in[2];
    float* out        = (float*)d_out;

    int N = in_sizes[2];            // 4096
    int K = in_sizes[1] / N;        // 4096
    int M = in_sizes[0] / K;        // 8192

    unsigned* amax      = (unsigned*)d_ws;
    unsigned short* xq  = (unsigned short*)((char*)d_ws + 256);                 // [M][K]
    unsigned short* wqT = (unsigned short*)((char*)xq + (size_t)M * K * 2);     // [N][K]

    hipMemsetAsync(d_ws, 0, 256, stream);

    long long nx4 = (long long)M * K / 4;
    long long nw4 = (long long)K * N / 4;

    absmax_kernel<<<1024, 256, 0, stream>>>((const float4*)x, nx4, amax + 0);
    absmax_kernel<<<1024, 256, 0, stream>>>((const float4*)w, nw4, amax + 1);

    quant_kernel<<<2048, 256, 0, stream>>>((const float4*)x, amax + 0, (ushort4*)xq, nx4);
    quant_w_t_kernel<<<dim3(K / 64, N / 64), 256, 0, stream>>>(w, amax + 1, wqT, N, K);

    dim3 grid((M / 256) * (N / 256));   // 512 blocks
    gemm256_kernel<<<grid, 512, 0, stream>>>(xq, wqT, amax, bias, out, M, N, K);
}